// Round 3
// baseline (81.258 us; speedup 1.0000x reference)
//
#include <hip/hip_runtime.h>

// Bernstein->monomial basis change, degree 5, with input remap t=(x+1)/2 folded in:
// B_i((x+1)/2) = sum_d Mb[i][d] * x^d   (entries exact in fp32: integer/32)
__device__ __constant__ float Mb[6][6] = {
    { 0.03125f, -0.15625f,  0.3125f, -0.3125f,  0.15625f, -0.03125f},
    { 0.15625f, -0.46875f,  0.3125f,  0.3125f, -0.46875f,  0.15625f},
    { 0.3125f,  -0.3125f,  -0.625f,   0.625f,   0.3125f,  -0.3125f },
    { 0.3125f,   0.3125f,  -0.625f,  -0.625f,   0.3125f,   0.3125f },
    { 0.15625f,  0.46875f,  0.3125f, -0.3125f, -0.46875f, -0.15625f},
    { 0.03125f,  0.15625f,  0.3125f,  0.3125f,  0.15625f,  0.03125f},
};

// Fused kernel, 8 vertices/thread.
// Phase 1: every block converts p[3][6][6][6] (Bernstein) -> monomial coeffs in
// its own LDS (redundant across blocks, ~12k FMAs, free).
// Phase 2: nested Horner. Per (c,i) iteration: 9x ds_read_b128 (uniform addr ->
// broadcast) then 248 straight-line FMAs over 8 vertices. 32:1 VALU:DS ratio
// keeps the per-CU LDS pipe (~12 cyc/b128) below the VALU time — at 4 verts/
// thread the DS pipe was the binding resource (162 reads/wave x 12 cyc x 15
// waves/CU ~ 12.4us > 8.4us VALU).
__global__ __launch_bounds__(256) void ffd_fused(const float* __restrict__ verts,
                                                 const float* __restrict__ p,
                                                 float* __restrict__ out, int N)
{
    __shared__ __align__(16) float b0[648];
    __shared__ __align__(16) float b1[648];
    const int t = threadIdx.x;

    // ---- Phase 1: separable basis change in LDS ----
    for (int m = t; m < 648; m += 256) b0[m] = p[m];
    __syncthreads();

    // k -> dk  (b0 -> b1)
    for (int m = t; m < 648; m += 256) {
        const int dk = m % 6;
        const int base = (m / 6) * 6;
        float s = 0.f;
        #pragma unroll
        for (int k = 0; k < 6; ++k) s = fmaf(b0[base + k], Mb[k][dk], s);
        b1[m] = s;
    }
    __syncthreads();

    // j -> dj  (b1 -> b0)
    for (int m = t; m < 648; m += 256) {
        const int dk = m % 6;
        const int dj = (m / 6) % 6;
        const int ci = m / 36;               // ci = c*6 + i
        float s = 0.f;
        #pragma unroll
        for (int j = 0; j < 6; ++j) s = fmaf(b1[(ci * 6 + j) * 6 + dk], Mb[j][dj], s);
        b0[m] = s;
    }
    __syncthreads();

    // i -> di, fold in q' = 2q - 1  (b0 -> b1). b1 = final coeffs A[c][i][j][k].
    for (int m = t; m < 648; m += 256) {
        const int dk = m % 6;
        const int dj = (m / 6) % 6;
        const int di = (m / 36) % 6;
        const int c  = m / 216;
        float s = 0.f;
        #pragma unroll
        for (int i = 0; i < 6; ++i) s = fmaf(b0[((c * 6 + i) * 6 + dj) * 6 + dk], Mb[i][di], s);
        s *= 2.0f;
        if (di == 0 && dj == 0 && dk == 0) s -= 1.0f;
        b1[m] = s;
    }
    __syncthreads();

    // ---- Phase 2: evaluation, 8 vertices per thread ----
    const long long v0 = ((long long)blockIdx.x * 256 + t) * 8;
    if (v0 >= N) return;

    float x[8], y[8], z[8];
    const bool full = (v0 + 8 <= N);
    if (full) {
        const float4* vp = (const float4*)(verts + v0 * 3);  // 96B offset -> 16B aligned
        float4 f[6];
        #pragma unroll
        for (int r = 0; r < 6; ++r) f[r] = vp[r];
        const float* ff = (const float*)f;
        #pragma unroll
        for (int v = 0; v < 8; ++v) {
            x[v] = ff[v * 3 + 0]; y[v] = ff[v * 3 + 1]; z[v] = ff[v * 3 + 2];
        }
    } else {
        #pragma unroll
        for (int v = 0; v < 8; ++v) {
            long long n = v0 + v; if (n >= N) n = N - 1;
            x[v] = verts[n * 3 + 0]; y[v] = verts[n * 3 + 1]; z[v] = verts[n * 3 + 2];
        }
    }

    float res[24];
    #pragma unroll 1
    for (int c = 0; c < 3; ++c) {
        float q[8];
        #pragma unroll 1
        for (int ii = 0; ii < 6; ++ii) {
            const int i = 5 - ii;
            // 36 coeffs for this (c,i): 9x ds_read_b128, uniform addr (broadcast).
            const float4* blk = (const float4*)(b1 + (c * 6 + i) * 36);
            float a[36];
            #pragma unroll
            for (int r = 0; r < 9; ++r) {
                const float4 f = blk[r];
                a[r * 4 + 0] = f.x; a[r * 4 + 1] = f.y;
                a[r * 4 + 2] = f.z; a[r * 4 + 3] = f.w;
            }
            float tj[8];
            #pragma unroll
            for (int jj = 0; jj < 6; ++jj) {
                const int j = 5 - jj;
                const float* Ak = a + j * 6;
                #pragma unroll
                for (int v = 0; v < 8; ++v) {
                    float s = fmaf(Ak[5], z[v], Ak[4]);
                    s = fmaf(s, z[v], Ak[3]);
                    s = fmaf(s, z[v], Ak[2]);
                    s = fmaf(s, z[v], Ak[1]);
                    s = fmaf(s, z[v], Ak[0]);
                    tj[v] = (jj == 0) ? s : fmaf(tj[v], y[v], s);
                }
            }
            #pragma unroll
            for (int v = 0; v < 8; ++v)
                q[v] = (ii == 0) ? tj[v] : fmaf(q[v], x[v], tj[v]);
        }
        #pragma unroll
        for (int v = 0; v < 8; ++v) res[v * 3 + c] = q[v];
    }

    if (full) {
        float4* op = (float4*)(out + v0 * 3);
        #pragma unroll
        for (int r = 0; r < 6; ++r)
            op[r] = make_float4(res[r * 4 + 0], res[r * 4 + 1],
                                res[r * 4 + 2], res[r * 4 + 3]);
    } else {
        #pragma unroll
        for (int v = 0; v < 8; ++v) {
            const long long n = v0 + v;
            if (n < N) {
                out[n * 3 + 0] = res[v * 3 + 0];
                out[n * 3 + 1] = res[v * 3 + 1];
                out[n * 3 + 2] = res[v * 3 + 2];
            }
        }
    }
}

extern "C" void kernel_launch(void* const* d_in, const int* in_sizes, int n_in,
                              void* d_out, int out_size, void* d_ws, size_t ws_size,
                              hipStream_t stream)
{
    const float* verts = (const float*)d_in[0];   // [N,3] fp32
    const float* p     = (const float*)d_in[1];   // [3,6,6,6] fp32
    float* out = (float*)d_out;                   // [1,N,3] fp32
    const int N = in_sizes[0] / 3;

    const int threads_needed = (N + 7) / 8;
    const int blocks = (threads_needed + 255) / 256;
    ffd_fused<<<blocks, 256, 0, stream>>>(verts, p, out, N);
}